// Round 1
// 4631.035 us; speedup vs baseline: 1.0112x; 1.0112x over previous
//
#include <hip/hip_runtime.h>
#include <hip/hip_fp16.h>

// ---------------------------------------------------------------------------
// LSTM position predictor, persistent cooperative kernel. Round 4.
//   KEY CHANGES vs round 3 (theory: 96% of each step is serialized latency):
//   1) Sync rewrite: RMW-cascade arrival + leader/xcdgen relay replaced by
//      store-based arrival slots (bar[bid]) + one aggregator wave (block 0)
//      that bypass-reads all 256 slots and broadcasts a release to 32 spread
//      lines. Every block then does its OWN buffer_inv sc0 sc1 (round 2
//      showed per-block inv == per-XCD inv in cost). ~2 IF hops vs ~5.
//   2) Deep prefetch: all 32 h16 A-fragment loads (512 B/lane) issued into
//      registers at step top, before the gbuf phases; intra-step barriers are
//      raw s_barrier + lgkmcnt(0) so the compiler's vmcnt(0)-before-s_barrier
//      does not drain the prefetch.
//   3) fc fused into the GEMM: out = h @ fc_W.T computed redundantly per
//      block from the SAME prefetched A registers via 2 extra MFMAs/K-chunk
//      against a zero-padded fc_W^T LDS tile. Deletes the obg global-atomic
//      reduction (65K IF RMWs per decoder step), its zeroing and assembly.
// ---------------------------------------------------------------------------

#define HID   2048
#define NBAT  64
#define TENC  128
#define TDEC  64
#define NBLK  256
#define NTHR  512
#define WROW  2056   // f16 per LDS weight row (+8 pad, 16B aligned)
#define FROW  2056   // f16 per fcT row (+8 pad breaks 4-way bank conflict)

typedef _Float16 f16;
typedef _Float16 f16x8 __attribute__((ext_vector_type(8)));
typedef _Float16 f16x4 __attribute__((ext_vector_type(4)));
typedef float    f32x4v __attribute__((ext_vector_type(4)));

// LDS layout (bytes):
//   0      : wlds  32 x 2056 f16      = 131584
//   131584 : gbuf  [64][36] f32       =   9216
//   140800 : xv    [64][4]  f32       =   1024
//   141824 : wsm   [32][4]  f32       =    512
//   142336 : bsm   [32]     f32       =    128
//   142464 : fcp   [64][4]  f32       =   1024
//   143488 : fcT   [4][2056] f16      =  16448
#define SMEM_BYTES 159936

struct Params {
  const float* x; const int* lengths;
  const float* enc_Wih; const float* enc_Whh; const float* enc_bih; const float* enc_bhh;
  const float* emb_W; const float* emb_b;
  const float* dec_Wih; const float* dec_Whh; const float* dec_bih; const float* dec_bhh;
  const float* fc_W; const float* fc_b;
  float* dst;        // 278784 floats: preds[64][64][4], out[64][4], h[64][2048], c[64][2048]
  f16* h16;          // ws: [2][64][2048] double-buffered hidden state
  unsigned* bar;     // ws: arrival slots [0..255], release lines at 512 + g*32 (g<32)
};

__device__ __forceinline__ void astore_u32(unsigned* p, unsigned v) {
  __hip_atomic_store(p, v, __ATOMIC_RELAXED, __HIP_MEMORY_SCOPE_AGENT);
}
__device__ __forceinline__ void astore_u64(float* p, unsigned long long v) {
  __hip_atomic_store((unsigned long long*)p, v, __ATOMIC_RELAXED, __HIP_MEMORY_SCOPE_AGENT);
}
__device__ __forceinline__ unsigned aload_u32(const unsigned* p) {
  return __hip_atomic_load(p, __ATOMIC_RELAXED, __HIP_MEMORY_SCOPE_AGENT);
}
__device__ __forceinline__ uint4 aload_u32x4(const unsigned* p) {
  uint4 r;
  asm volatile("global_load_dwordx4 %0, %1, off sc0 sc1\n\ts_waitcnt vmcnt(0)"
               : "=v"(r) : "v"(p) : "memory");
  return r;
}

// Block-local barrier that drains ONLY LDS (keeps vmem prefetch in flight).
__device__ __forceinline__ void ldsbar() {
  asm volatile("s_waitcnt lgkmcnt(0)" ::: "memory");
  __builtin_amdgcn_s_barrier();
}

// Grid barrier: store arrival -> block0 wave0 aggregates -> spread release ->
// every block invalidates its own L1+L2 (stale h16 lines), then proceeds.
__device__ __forceinline__ void gbar(unsigned* bar, unsigned& target, int bid) {
  __syncthreads();   // drains this block's vmem stores (h16) before arrival
  if (bid == 0) {
    if (threadIdx.x == 0) astore_u32(&bar[0], target);
    if (threadIdx.x < 64) {
      const unsigned* slots = bar + threadIdx.x * 4;
      for (;;) {
        uint4 v = aload_u32x4(slots);
        int ok = (v.x >= target) & (v.y >= target) & (v.z >= target) & (v.w >= target);
        if (__all(ok)) break;
        __builtin_amdgcn_s_sleep(1);
      }
      if (threadIdx.x < 32) astore_u32(&bar[512 + threadIdx.x * 32], target);
    }
  } else if (threadIdx.x == 0) {
    astore_u32(&bar[bid], target);
    while (aload_u32(&bar[512 + (bid >> 3) * 32]) < target)
      __builtin_amdgcn_s_sleep(1);
  }
  if (threadIdx.x == 0)
    asm volatile("s_waitcnt vmcnt(0)\n\t"
                 "buffer_inv sc0 sc1\n\t"
                 "s_waitcnt vmcnt(0)" ::: "memory");
  __syncthreads();
  target++;
}

// Convert this block's 32 gate rows of W (fp32 [8192][2048]) into LDS fp16.
__device__ __forceinline__ void fill_weights(const float* __restrict__ W, int bid,
                                             f16* wlds, int w, int l) {
  #pragma unroll
  for (int rr = 0; rr < 4; ++rr) {
    int r  = w * 4 + rr;
    int gr = ((r >> 3) << 11) + bid * 8 + (r & 7);
    const float4* src = (const float4*)(W + (size_t)gr * HID);
    f16* dst = wlds + (size_t)r * WROW;
    #pragma unroll
    for (int it = 0; it < 8; ++it) {
      float4 v = src[it * 64 + l];
      f16x4 h4; h4[0] = (f16)v.x; h4[1] = (f16)v.y; h4[2] = (f16)v.z; h4[3] = (f16)v.w;
      *(f16x4*)(dst + (it * 64 + l) * 4) = h4;
    }
  }
}

// Issue ALL h16 A-fragment loads for this wave into registers (128 VGPRs).
__device__ __forceinline__ void gemm_prefetch(const f16* __restrict__ h16p,
                                              int w, int l15, int quad,
                                              f16x8* pa0, f16x8* pa1) {
  const int mh = w & 1, kq = w >> 1;
  const f16* A0 = h16p + (size_t)(mh * 32 + l15) * HID + kq * 512 + quad * 8;
  const f16* A1 = A0 + (size_t)16 * HID;
  #pragma unroll
  for (int ch = 0; ch < 16; ++ch) {
    pa0[ch] = *(const f16x8*)(A0 + ch * 32);
    pa1[ch] = *(const f16x8*)(A1 + ch * 32);
  }
}

// fc partial: out[b][d] += sum_k h[b][k] * fcW[d][k] over this wave's fragment.
__device__ __forceinline__ void fc_compute(const f16* fcT, float* fcp,
                                           int w, int l15, int quad,
                                           const f16x8* pa0, const f16x8* pa1) {
  const int mh = w & 1, kq = w >> 1;
  f32x4v f0 = {0.f, 0.f, 0.f, 0.f}, f1 = f0;
  const f16* BF = fcT + (size_t)l15 * FROW + kq * 512 + quad * 8;
  #pragma unroll
  for (int ch = 0; ch < 16; ++ch) {
    f16x8 vbF = {};
    if (l15 < 4) vbF = *(const f16x8*)(BF + ch * 32);
    f0 = __builtin_amdgcn_mfma_f32_16x16x32_f16(pa0[ch], vbF, f0, 0, 0, 0);
    f1 = __builtin_amdgcn_mfma_f32_16x16x32_f16(pa1[ch], vbF, f1, 0, 0, 0);
  }
  if (l15 < 4) {
    const int brow = mh * 32 + quad * 4;
    #pragma unroll
    for (int r = 0; r < 4; ++r) {
      unsafeAtomicAdd(&fcp[(brow + r) * 4 + l15],      f0[r]);
      unsafeAtomicAdd(&fcp[(brow + 16 + r) * 4 + l15], f1[r]);
    }
  }
}

// gates += h @ Whh.T for this block's 32 gate rows; optional fused fc partial.
template<bool FC>
__device__ __forceinline__ void gemm_compute(const f16* wlds, const f16* fcT,
                                             float* gbuf, float* fcp,
                                             int w, int l15, int quad,
                                             const f16x8* pa0, const f16x8* pa1) {
  const int mh = w & 1, kq = w >> 1;
  f32x4v a00 = {0.f, 0.f, 0.f, 0.f}, a01 = a00, a10 = a00, a11 = a00;
  const f16* B0 = wlds + (size_t)l15 * WROW + kq * 512 + quad * 8;
  const f16* B1 = B0 + (size_t)16 * WROW;
  #pragma unroll
  for (int ch = 0; ch < 16; ++ch) {
    f16x8 vb0 = *(const f16x8*)(B0 + ch * 32);
    f16x8 vb1 = *(const f16x8*)(B1 + ch * 32);
    a00 = __builtin_amdgcn_mfma_f32_16x16x32_f16(pa0[ch], vb0, a00, 0, 0, 0);
    a01 = __builtin_amdgcn_mfma_f32_16x16x32_f16(pa0[ch], vb1, a01, 0, 0, 0);
    a10 = __builtin_amdgcn_mfma_f32_16x16x32_f16(pa1[ch], vb0, a10, 0, 0, 0);
    a11 = __builtin_amdgcn_mfma_f32_16x16x32_f16(pa1[ch], vb1, a11, 0, 0, 0);
  }
  const int brow = mh * 32 + quad * 4;
  #pragma unroll
  for (int r = 0; r < 4; ++r) {
    unsafeAtomicAdd(&gbuf[(brow + r)      * 36 +      l15], a00[r]);
    unsafeAtomicAdd(&gbuf[(brow + r)      * 36 + 16 + l15], a01[r]);
    unsafeAtomicAdd(&gbuf[(brow + 16 + r) * 36 +      l15], a10[r]);
    unsafeAtomicAdd(&gbuf[(brow + 16 + r) * 36 + 16 + l15], a11[r]);
  }
  if (FC) fc_compute(fcT, fcp, w, l15, quad, pa0, pa1);
}

extern "C" __global__ void __launch_bounds__(NTHR, 2)
lstm_persistent(Params P) {
  extern __shared__ char smem[];
  f16*   wlds = (f16*)smem;
  float* gbuf = (float*)(smem + 131584);
  float* xv   = (float*)(smem + 140800);
  float* wsm  = (float*)(smem + 141824);
  float* bsm  = (float*)(smem + 142336);
  float* fcp  = (float*)(smem + 142464);
  f16*   fcT  = (f16*)(smem + 143488);

  const int t    = threadIdx.x;
  const int bid  = blockIdx.x;
  const int w    = t >> 6;
  const int l    = t & 63;
  const int l15  = l & 15;
  const int quad = l >> 4;
  const int bb   = t >> 3;
  const int jj   = t & 7;
  const int jglob = bid * 8 + jj;

  unsigned target = 1;

  // ---------------- setup (block-local) ----------------
  if (t < 32) {
    int r = t, gr = ((r >> 3) << 11) + bid * 8 + (r & 7);
    ((float4*)wsm)[r] = ((const float4*)P.enc_Wih)[gr];
    bsm[r] = P.enc_bih[gr] + P.enc_bhh[gr];
  }
  fill_weights(P.enc_Whh, bid, wlds, w, l);

  const int len_b = P.lengths[bb];
  const float4 fcb = ((const float4*)P.fc_b)[0];
  float hreg = 0.f, creg = 0.f;

  // ---------------- encoder: 128 masked steps ----------------
  for (int ts = 0; ts < TENC; ++ts) {
    const int rp = ts & 1, wp = (ts + 1) & 1;
    float4 xvv;
    if (t < NBAT) xvv = ((const float4*)P.x)[t * TENC + ts];   // issue before prefetch
    f16x8 pa0[16], pa1[16];
    if (ts > 0) gemm_prefetch(P.h16 + (size_t)rp * NBAT * HID, w, l15, quad, pa0, pa1);
    if (t < NBAT) ((float4*)xv)[t] = xvv;
    ldsbar();
    for (int e = t; e < 2048; e += NTHR) {      // gbuf = bias + rank-4 input
      int b = e >> 5, n = e & 31;
      float4 wv = ((const float4*)wsm)[n];
      const float* xb = xv + b * 4;
      gbuf[b * 36 + n] = bsm[n] + xb[0] * wv.x + xb[1] * wv.y + xb[2] * wv.z + xb[3] * wv.w;
    }
    ldsbar();
    if (ts > 0) gemm_compute<false>(wlds, fcT, gbuf, fcp, w, l15, quad, pa0, pa1);
    ldsbar();
    {
      float gi = gbuf[bb * 36 + jj],      gf = gbuf[bb * 36 + 8 + jj];
      float gg = gbuf[bb * 36 + 16 + jj], go = gbuf[bb * 36 + 24 + jj];
      float ii = 1.f / (1.f + expf(-gi));
      float ff = 1.f / (1.f + expf(-gf));
      float g  = tanhf(gg);
      float oo = 1.f / (1.f + expf(-go));
      float cn = ff * creg + ii * g;
      float hn = oo * tanhf(cn);
      if (ts < len_b) { creg = cn; hreg = hn; }   // packed-sequence freeze
      unsigned hv = (unsigned)__builtin_bit_cast(unsigned short, (f16)hreg);
      unsigned v1 = __shfl_down(hv, 1), v2 = __shfl_down(hv, 2), v3 = __shfl_down(hv, 3);
      if ((t & 3) == 0) {
        unsigned long long pk = (unsigned long long)hv | ((unsigned long long)v1 << 16)
                              | ((unsigned long long)v2 << 32) | ((unsigned long long)v3 << 48);
        astore_u64((float*)(P.h16 + (size_t)wp * NBAT * HID + (size_t)bb * HID + bid * 8 + (jj & 4)), pk);
      }
    }
    gbar(P.bar, target, bid);
  }

  // ---------------- transition: decoder weights + folded M1 + fcT ----------------
  fill_weights(P.dec_Whh, bid, wlds, w, l);
  #pragma unroll
  for (int rr = 0; rr < 4; ++rr) {       // M1 = dec_Wih@emb_W straight into LDS
    int r = w * 4 + rr, gr = ((r >> 3) << 11) + bid * 8 + (r & 7);
    const float* wr = P.dec_Wih + (size_t)gr * HID;
    float a0 = 0.f, a1 = 0.f, a2 = 0.f, a3 = 0.f, ab = 0.f;
    for (int k = l; k < HID; k += 64) {
      float wv = wr[k];
      float4 e = ((const float4*)P.emb_W)[k];
      a0 += wv * e.x; a1 += wv * e.y; a2 += wv * e.z; a3 += wv * e.w;
      ab += wv * P.emb_b[k];
    }
    #pragma unroll
    for (int off = 32; off > 0; off >>= 1) {
      a0 += __shfl_xor(a0, off); a1 += __shfl_xor(a1, off);
      a2 += __shfl_xor(a2, off); a3 += __shfl_xor(a3, off);
      ab += __shfl_xor(ab, off);
    }
    if (l == 0) {
      wsm[r * 4 + 0] = a0; wsm[r * 4 + 1] = a1; wsm[r * 4 + 2] = a2; wsm[r * 4 + 3] = a3;
      bsm[r] = ab + P.dec_bih[gr] + P.dec_bhh[gr];
    }
  }
  for (int i = t; i < 2048; i += NTHR) {   // fcT[d][k] = (f16)fc_W[d][k]
    int d = i >> 9, k4 = i & 511;
    float4 v = ((const float4*)P.fc_W)[i];
    f16x4 h4; h4[0] = (f16)v.x; h4[1] = (f16)v.y; h4[2] = (f16)v.z; h4[3] = (f16)v.w;
    *(f16x4*)(fcT + (size_t)d * FROW + k4 * 4) = h4;
  }
  ldsbar();   // block-local: wlds/wsm/bsm/fcT visible (no grid sync needed here)

  // ---------------- decoder: 64 autoregressive steps ----------------
  for (int s = 0; s < TDEC; ++s) {
    const int rp = s & 1, wp = (s + 1) & 1;
    f16x8 pa0[16], pa1[16];
    gemm_prefetch(P.h16 + (size_t)rp * NBAT * HID, w, l15, quad, pa0, pa1);
    if (t < 256) fcp[t] = 0.f;
    for (int e = t; e < 2048; e += NTHR) {      // gbuf = bias only (rank-4 added later)
      int b = e >> 5, n = e & 31;
      gbuf[b * 36 + n] = bsm[n];
    }
    ldsbar();
    gemm_compute<true>(wlds, fcT, gbuf, fcp, w, l15, quad, pa0, pa1);
    ldsbar();
    if (t < NBAT) {          // xv = input for this step = fc(h_prev) (or x0 at s==0)
      float4 o;
      if (s == 0) {
        o = ((const float4*)P.x)[t * TENC + (P.lengths[t] - 1)];
      } else {
        float4 p = ((const float4*)fcp)[t];
        o.x = fcb.x + p.x; o.y = fcb.y + p.y; o.z = fcb.z + p.z; o.w = fcb.w + p.w;
      }
      ((float4*)xv)[t] = o;
      if (s >= 1 && bid == s)                   // rotating prediction writer
        ((float4*)P.dst)[t * TDEC + (s - 1)] = o;
    }
    ldsbar();
    for (int e = t; e < 2048; e += NTHR) {      // gbuf += rank-4(xv, M1)
      int b = e >> 5, n = e & 31;
      float4 wv = ((const float4*)wsm)[n];
      const float* xb = xv + b * 4;
      gbuf[b * 36 + n] += xb[0] * wv.x + xb[1] * wv.y + xb[2] * wv.z + xb[3] * wv.w;
    }
    ldsbar();
    {
      float gi = gbuf[bb * 36 + jj],      gf = gbuf[bb * 36 + 8 + jj];
      float gg = gbuf[bb * 36 + 16 + jj], go = gbuf[bb * 36 + 24 + jj];
      float ii = 1.f / (1.f + expf(-gi));
      float ff = 1.f / (1.f + expf(-gf));
      float g  = tanhf(gg);
      float oo = 1.f / (1.f + expf(-go));
      creg = ff * creg + ii * g;
      hreg = oo * tanhf(creg);
      unsigned hv = (unsigned)__builtin_bit_cast(unsigned short, (f16)hreg);
      unsigned v1 = __shfl_down(hv, 1), v2 = __shfl_down(hv, 2), v3 = __shfl_down(hv, 3);
      if ((t & 3) == 0) {
        unsigned long long pk = (unsigned long long)hv | ((unsigned long long)v1 << 16)
                              | ((unsigned long long)v2 << 32) | ((unsigned long long)v3 << 48);
        astore_u64((float*)(P.h16 + (size_t)wp * NBAT * HID + (size_t)bb * HID + bid * 8 + (jj & 4)), pk);
      }
    }
    gbar(P.bar, target, bid);
  }

  // ---------------- epilogue: out(63) = fc(H_63) by block 0 ----------------
  if (bid == 0) {
    if (t < 256) fcp[t] = 0.f;
    ldsbar();
    f16x8 pa0[16], pa1[16];
    gemm_prefetch(P.h16 + (size_t)(TDEC & 1) * NBAT * HID, w, l15, quad, pa0, pa1);
    fc_compute(fcT, fcp, w, l15, quad, pa0, pa1);
    ldsbar();
    if (t < NBAT) {
      float4 p = ((const float4*)fcp)[t];
      float4 o;
      o.x = fcb.x + p.x; o.y = fcb.y + p.y; o.z = fcb.z + p.z; o.w = fcb.w + p.w;
      ((float4*)P.dst)[t * TDEC + 63] = o;       // predictions[b][63]
      ((float4*)(P.dst + 16384))[t]   = o;       // out
    }
  }
  P.dst[16640  + (size_t)bb * HID + jglob] = hreg;   // h
  P.dst[147712 + (size_t)bb * HID + jglob] = creg;   // c
}

extern "C" void kernel_launch(void* const* d_in, const int* in_sizes, int n_in,
                              void* d_out, int out_size, void* d_ws, size_t ws_size,
                              hipStream_t stream) {
  (void)in_sizes; (void)n_in; (void)out_size; (void)ws_size;
  Params P;
  P.x        = (const float*)d_in[0];
  P.lengths  = (const int*)  d_in[1];
  // d_in[2] = target_len (constant 64)
  P.enc_Wih  = (const float*)d_in[3];
  P.enc_Whh  = (const float*)d_in[4];
  P.enc_bih  = (const float*)d_in[5];
  P.enc_bhh  = (const float*)d_in[6];
  P.emb_W    = (const float*)d_in[7];
  P.emb_b    = (const float*)d_in[8];
  P.dec_Wih  = (const float*)d_in[9];
  P.dec_Whh  = (const float*)d_in[10];
  P.dec_bih  = (const float*)d_in[11];
  P.dec_bhh  = (const float*)d_in[12];
  P.fc_W     = (const float*)d_in[13];
  P.fc_b     = (const float*)d_in[14];
  P.dst      = (float*)d_out;

  char* ws = (char*)d_ws;
  P.h16 = (f16*)ws;                                  // 2*64*2048*2 = 524288 B
  P.bar = (unsigned*)(ws + 524288);                  // 12288 B

  hipMemsetAsync(P.bar, 0, 12288, stream);           // ws is poisoned 0xAA

  hipFuncSetAttribute((const void*)lstm_persistent,
                      hipFuncAttributeMaxDynamicSharedMemorySize, SMEM_BYTES);
  void* args[] = { &P };
  hipLaunchCooperativeKernel((const void*)lstm_persistent, dim3(NBLK), dim3(NTHR),
                             args, SMEM_BYTES, stream);
}

// Round 3
// 4301.738 us; speedup vs baseline: 1.0886x; 1.0765x over previous
//
#include <hip/hip_runtime.h>
#include <hip/hip_fp16.h>

// ---------------------------------------------------------------------------
// LSTM position predictor, persistent cooperative kernel. Round 6.
//   Round 5 hung (suspect: novel "L2-local" atomic sync — flag-less atomics
//   may execute at IF while the leader polled a stale L2 copy -> deadlock).
//   Round 6 re-tests the round-5 HYPOTHESIS (per-step buffer_inv L2 wipe +
//   cold refetch is the ~23us/step term) with a MINIMAL delta from the
//   last PASSING kernel (round 4):
//   1) h16 is a write-once RING of 193 generation buffers (50.6 MB ws):
//      step t writes gen t+1, reads gen t. No address is ever rewritten ->
//      no stale-copy hazard -> plain cached loads (L2 multicast per XCD),
//      ZERO steady-state invalidates. Fallback to 2-buffer + sc0 sc1 bypass
//      loads if ws is too small (also inv-free).
//   2) ONE-TIME buffer_inv sc0 sc1 per block at kernel entry (clears
//      cross-dispatch stale lines). Race-free: no dirty lines exist at
//      entry (all sync ops are write-through/bypass; h16 stores are sc1
//      write-through; dst dirty stores only begin in the decoder).
//   Sync is round-4's PROVEN gbar (store slots + block-0 aggregator +
//   spread release) minus its per-step buffer_inv. Everything else is
//   byte-identical to round 4 (passed, 4631 us).
// ---------------------------------------------------------------------------

#define HID   2048
#define NBAT  64
#define TENC  128
#define TDEC  64
#define NBLK  256
#define NTHR  512
#define WROW  2056   // f16 per LDS weight row (+8 pad, 16B aligned)
#define FROW  2056   // f16 per fcT row

typedef _Float16 f16;
typedef _Float16 f16x8 __attribute__((ext_vector_type(8)));
typedef _Float16 f16x4 __attribute__((ext_vector_type(4)));
typedef float    f32x4v __attribute__((ext_vector_type(4)));

// LDS layout (bytes):
//   0      : wlds  32 x 2056 f16      = 131584
//   131584 : gbuf  [64][36] f32       =   9216
//   140800 : xv    [64][4]  f32       =   1024
//   141824 : wsm   [32][4]  f32       =    512
//   142336 : bsm   [32]     f32       =    128
//   142464 : fcp   [64][4]  f32       =   1024
//   143488 : fcT   [4][2056] f16      =  16448
#define SMEM_BYTES 159936

struct Params {
  const float* x; const int* lengths;
  const float* enc_Wih; const float* enc_Whh; const float* enc_bih; const float* enc_bhh;
  const float* emb_W; const float* emb_b;
  const float* dec_Wih; const float* dec_Whh; const float* dec_bih; const float* dec_bhh;
  const float* fc_W; const float* fc_b;
  float* dst;        // 278784 floats: preds[64][64][4], out[64][4], h[64][2048], c[64][2048]
  f16* h16;          // ws: ring of 193 gen buffers (or 2 in fallback), 64x2048 f16 each
  unsigned* bar;     // ws: arrival slots [0..255], release lines at 512 + g*32 (g<32)
  int ring;          // 1 = write-once ring (no inv, cached reads); 0 = 2-buf bypass
};

__device__ __forceinline__ void astore_u32(unsigned* p, unsigned v) {
  __hip_atomic_store(p, v, __ATOMIC_RELAXED, __HIP_MEMORY_SCOPE_AGENT);
}
__device__ __forceinline__ void astore_u64(float* p, unsigned long long v) {
  __hip_atomic_store((unsigned long long*)p, v, __ATOMIC_RELAXED, __HIP_MEMORY_SCOPE_AGENT);
}
__device__ __forceinline__ unsigned aload_u32(const unsigned* p) {
  return __hip_atomic_load(p, __ATOMIC_RELAXED, __HIP_MEMORY_SCOPE_AGENT);
}
__device__ __forceinline__ uint4 aload_u32x4(const unsigned* p) {
  uint4 r;
  asm volatile("global_load_dwordx4 %0, %1, off sc0 sc1\n\ts_waitcnt vmcnt(0)"
               : "=v"(r) : "v"(p) : "memory");
  return r;
}
__device__ __forceinline__ f16x8 bload_f16x8(const f16* p) {   // IF-bypass load, left in flight
  f16x8 r;
  asm volatile("global_load_dwordx4 %0, %1, off sc0 sc1" : "=v"(r) : "v"(p));
  return r;
}

// Block-local barrier that drains ONLY LDS (keeps vmem prefetch in flight).
__device__ __forceinline__ void ldsbar() {
  asm volatile("s_waitcnt lgkmcnt(0)" ::: "memory");
  __builtin_amdgcn_s_barrier();
}
// Drain prefetch before MFMA use; fence against MFMA hoisting (rule #18).
__device__ __forceinline__ void waitpa() {
  asm volatile("s_waitcnt vmcnt(0)" ::: "memory");
  __builtin_amdgcn_sched_barrier(0);
}

// Grid barrier (round-4 proven): store arrival -> block0 wave0 aggregates ->
// spread release. NO cache invalidate (the h16 ring makes it unnecessary).
__device__ __forceinline__ void gbar(unsigned* bar, unsigned& target, int bid) {
  __syncthreads();   // drains this block's vmem stores (h16, sc1 write-through)
  if (bid == 0) {
    if (threadIdx.x == 0) astore_u32(&bar[0], target);
    if (threadIdx.x < 64) {
      const unsigned* slots = bar + threadIdx.x * 4;
      for (;;) {
        uint4 v = aload_u32x4(slots);
        int ok = (v.x >= target) & (v.y >= target) & (v.z >= target) & (v.w >= target);
        if (__all(ok)) break;
        __builtin_amdgcn_s_sleep(1);
      }
      if (threadIdx.x < 32) astore_u32(&bar[512 + threadIdx.x * 32], target);
    }
  } else if (threadIdx.x == 0) {
    astore_u32(&bar[bid], target);
    while (aload_u32(&bar[512 + (bid >> 3) * 32]) < target)
      __builtin_amdgcn_s_sleep(1);
  }
  __syncthreads();
  target++;
}

// Convert this block's 32 gate rows of W (fp32 [8192][2048]) into LDS fp16.
__device__ __forceinline__ void fill_weights(const float* __restrict__ W, int bid,
                                             f16* wlds, int w, int l) {
  #pragma unroll
  for (int rr = 0; rr < 4; ++rr) {
    int r  = w * 4 + rr;
    int gr = ((r >> 3) << 11) + bid * 8 + (r & 7);
    const float4* src = (const float4*)(W + (size_t)gr * HID);
    f16* dst = wlds + (size_t)r * WROW;
    #pragma unroll
    for (int it = 0; it < 8; ++it) {
      float4 v = src[it * 64 + l];
      f16x4 h4; h4[0] = (f16)v.x; h4[1] = (f16)v.y; h4[2] = (f16)v.z; h4[3] = (f16)v.w;
      *(f16x4*)(dst + (it * 64 + l) * 4) = h4;
    }
  }
}

// Issue ALL h16 A-fragment loads for this wave into registers.
__device__ __forceinline__ void gemm_prefetch(const f16* __restrict__ hp, int ring,
                                              int w, int l15, int quad,
                                              f16x8* pa0, f16x8* pa1) {
  const int mh = w & 1, kq = w >> 1;
  const f16* A0 = hp + (size_t)(mh * 32 + l15) * HID + kq * 512 + quad * 8;
  const f16* A1 = A0 + (size_t)16 * HID;
  if (ring) {           // write-once ring: cached loads, L2 multicast per XCD
    #pragma unroll
    for (int ch = 0; ch < 16; ++ch) {
      pa0[ch] = *(const f16x8*)(A0 + ch * 32);
      pa1[ch] = *(const f16x8*)(A1 + ch * 32);
    }
  } else {              // fallback: IF-bypass loads (no stale-L2 hazard)
    #pragma unroll
    for (int ch = 0; ch < 16; ++ch) {
      pa0[ch] = bload_f16x8(A0 + ch * 32);
      pa1[ch] = bload_f16x8(A1 + ch * 32);
    }
  }
}

// fc partial: out[b][d] += sum_k h[b][k] * fcW[d][k] over this wave's fragment.
__device__ __forceinline__ void fc_compute(const f16* fcT, float* fcp,
                                           int w, int l15, int quad,
                                           const f16x8* pa0, const f16x8* pa1) {
  const int mh = w & 1, kq = w >> 1;
  f32x4v f0 = {0.f, 0.f, 0.f, 0.f}, f1 = f0;
  const f16* BF = fcT + (size_t)l15 * FROW + kq * 512 + quad * 8;
  #pragma unroll
  for (int ch = 0; ch < 16; ++ch) {
    f16x8 vbF = {};
    if (l15 < 4) vbF = *(const f16x8*)(BF + ch * 32);
    f0 = __builtin_amdgcn_mfma_f32_16x16x32_f16(pa0[ch], vbF, f0, 0, 0, 0);
    f1 = __builtin_amdgcn_mfma_f32_16x16x32_f16(pa1[ch], vbF, f1, 0, 0, 0);
  }
  if (l15 < 4) {
    const int brow = mh * 32 + quad * 4;
    #pragma unroll
    for (int r = 0; r < 4; ++r) {
      unsafeAtomicAdd(&fcp[(brow + r) * 4 + l15],      f0[r]);
      unsafeAtomicAdd(&fcp[(brow + 16 + r) * 4 + l15], f1[r]);
    }
  }
}

// gates += h @ Whh.T for this block's 32 gate rows; optional fused fc partial.
template<bool FC>
__device__ __forceinline__ void gemm_compute(const f16* wlds, const f16* fcT,
                                             float* gbuf, float* fcp,
                                             int w, int l15, int quad,
                                             const f16x8* pa0, const f16x8* pa1) {
  const int mh = w & 1, kq = w >> 1;
  f32x4v a00 = {0.f, 0.f, 0.f, 0.f}, a01 = a00, a10 = a00, a11 = a00;
  const f16* B0 = wlds + (size_t)l15 * WROW + kq * 512 + quad * 8;
  const f16* B1 = B0 + (size_t)16 * WROW;
  #pragma unroll
  for (int ch = 0; ch < 16; ++ch) {
    f16x8 vb0 = *(const f16x8*)(B0 + ch * 32);
    f16x8 vb1 = *(const f16x8*)(B1 + ch * 32);
    a00 = __builtin_amdgcn_mfma_f32_16x16x32_f16(pa0[ch], vb0, a00, 0, 0, 0);
    a01 = __builtin_amdgcn_mfma_f32_16x16x32_f16(pa0[ch], vb1, a01, 0, 0, 0);
    a10 = __builtin_amdgcn_mfma_f32_16x16x32_f16(pa1[ch], vb0, a10, 0, 0, 0);
    a11 = __builtin_amdgcn_mfma_f32_16x16x32_f16(pa1[ch], vb1, a11, 0, 0, 0);
  }
  const int brow = mh * 32 + quad * 4;
  #pragma unroll
  for (int r = 0; r < 4; ++r) {
    unsafeAtomicAdd(&gbuf[(brow + r)      * 36 +      l15], a00[r]);
    unsafeAtomicAdd(&gbuf[(brow + r)      * 36 + 16 + l15], a01[r]);
    unsafeAtomicAdd(&gbuf[(brow + 16 + r) * 36 +      l15], a10[r]);
    unsafeAtomicAdd(&gbuf[(brow + 16 + r) * 36 + 16 + l15], a11[r]);
  }
  if (FC) fc_compute(fcT, fcp, w, l15, quad, pa0, pa1);
}

extern "C" __global__ void __launch_bounds__(NTHR, 2)
lstm_persistent(Params P) {
  extern __shared__ char smem[];
  f16*   wlds = (f16*)smem;
  float* gbuf = (float*)(smem + 131584);
  float* xv   = (float*)(smem + 140800);
  float* wsm  = (float*)(smem + 141824);
  float* bsm  = (float*)(smem + 142336);
  float* fcp  = (float*)(smem + 142464);
  f16*   fcT  = (f16*)(smem + 143488);

  const int t    = threadIdx.x;
  const int bid  = blockIdx.x;
  const int w    = t >> 6;
  const int l    = t & 63;
  const int l15  = l & 15;
  const int quad = l >> 4;
  const int bb   = t >> 3;
  const int jj   = t & 7;
  const int jglob = bid * 8 + jj;
  const int ring = P.ring;
  const size_t GEN = (size_t)NBAT * HID;   // f16 per generation buffer

  unsigned target = 1;

  // ---------------- one-time cache scrub (cross-dispatch stale lines) ------
  // Safe: no dirty lines exist anywhere at this point (sync = write-through/
  // bypass; h16 stores = sc1 write-through; dst stores start much later).
  // All blocks complete this before gbar #1, hence before any gen-1 read.
  if (t == 0)
    asm volatile("s_waitcnt vmcnt(0)\n\tbuffer_inv sc0 sc1\n\ts_waitcnt vmcnt(0)" ::: "memory");
  __syncthreads();

  // ---------------- setup (block-local) ----------------
  if (t < 32) {
    int r = t, gr = ((r >> 3) << 11) + bid * 8 + (r & 7);
    ((float4*)wsm)[r] = ((const float4*)P.enc_Wih)[gr];
    bsm[r] = P.enc_bih[gr] + P.enc_bhh[gr];
  }
  fill_weights(P.enc_Whh, bid, wlds, w, l);

  const int len_b = P.lengths[bb];
  const float4 fcb = ((const float4*)P.fc_b)[0];
  float hreg = 0.f, creg = 0.f;

  // ---------------- encoder: 128 masked steps ----------------
  for (int ts = 0; ts < TENC; ++ts) {
    const size_t roff = (size_t)(ring ? ts : (ts & 1)) * GEN;
    const size_t woff = (size_t)(ring ? (ts + 1) : ((ts + 1) & 1)) * GEN;
    float4 xvv;
    if (t < NBAT) xvv = ((const float4*)P.x)[t * TENC + ts];   // issue before prefetch
    f16x8 pa0[16], pa1[16];
    if (ts > 0) gemm_prefetch(P.h16 + roff, ring, w, l15, quad, pa0, pa1);
    if (t < NBAT) ((float4*)xv)[t] = xvv;
    ldsbar();
    for (int e = t; e < 2048; e += NTHR) {       // gbuf = bias + rank-4 input
      int b = e >> 5, n = e & 31;
      float4 wv = ((const float4*)wsm)[n];
      const float* xb = xv + b * 4;
      gbuf[b * 36 + n] = bsm[n] + xb[0] * wv.x + xb[1] * wv.y + xb[2] * wv.z + xb[3] * wv.w;
    }
    ldsbar();
    if (ts > 0) { waitpa(); gemm_compute<false>(wlds, fcT, gbuf, fcp, w, l15, quad, pa0, pa1); }
    ldsbar();
    {
      float gi = gbuf[bb * 36 + jj],      gf = gbuf[bb * 36 + 8 + jj];
      float gg = gbuf[bb * 36 + 16 + jj], go = gbuf[bb * 36 + 24 + jj];
      float ii = 1.f / (1.f + expf(-gi));
      float ff = 1.f / (1.f + expf(-gf));
      float g  = tanhf(gg);
      float oo = 1.f / (1.f + expf(-go));
      float cn = ff * creg + ii * g;
      float hn = oo * tanhf(cn);
      if (ts < len_b) { creg = cn; hreg = hn; }   // packed-sequence freeze
      unsigned hv = (unsigned)__builtin_bit_cast(unsigned short, (f16)hreg);
      unsigned v1 = __shfl_down(hv, 1), v2 = __shfl_down(hv, 2), v3 = __shfl_down(hv, 3);
      if ((t & 3) == 0) {
        unsigned long long pk = (unsigned long long)hv | ((unsigned long long)v1 << 16)
                              | ((unsigned long long)v2 << 32) | ((unsigned long long)v3 << 48);
        astore_u64((float*)(P.h16 + woff + (size_t)bb * HID + bid * 8 + (jj & 4)), pk);
      }
    }
    gbar(P.bar, target, bid);
  }

  // ---------------- transition: decoder weights + folded M1 + fcT ----------------
  fill_weights(P.dec_Whh, bid, wlds, w, l);
  #pragma unroll
  for (int rr = 0; rr < 4; ++rr) {       // M1 = dec_Wih@emb_W straight into LDS
    int r = w * 4 + rr, gr = ((r >> 3) << 11) + bid * 8 + (r & 7);
    const float* wr = P.dec_Wih + (size_t)gr * HID;
    float a0 = 0.f, a1 = 0.f, a2 = 0.f, a3 = 0.f, ab = 0.f;
    for (int k = l; k < HID; k += 64) {
      float wv = wr[k];
      float4 e = ((const float4*)P.emb_W)[k];
      a0 += wv * e.x; a1 += wv * e.y; a2 += wv * e.z; a3 += wv * e.w;
      ab += wv * P.emb_b[k];
    }
    #pragma unroll
    for (int off = 32; off > 0; off >>= 1) {
      a0 += __shfl_xor(a0, off); a1 += __shfl_xor(a1, off);
      a2 += __shfl_xor(a2, off); a3 += __shfl_xor(a3, off);
      ab += __shfl_xor(ab, off);
    }
    if (l == 0) {
      wsm[r * 4 + 0] = a0; wsm[r * 4 + 1] = a1; wsm[r * 4 + 2] = a2; wsm[r * 4 + 3] = a3;
      bsm[r] = ab + P.dec_bih[gr] + P.dec_bhh[gr];
    }
  }
  for (int i = t; i < 2048; i += NTHR) {   // fcT[d][k] = (f16)fc_W[d][k]
    int d = i >> 9, k4 = i & 511;
    float4 v = ((const float4*)P.fc_W)[i];
    f16x4 h4; h4[0] = (f16)v.x; h4[1] = (f16)v.y; h4[2] = (f16)v.z; h4[3] = (f16)v.w;
    *(f16x4*)(fcT + (size_t)d * FROW + k4 * 4) = h4;
  }
  ldsbar();   // block-local: wlds/wsm/bsm/fcT visible (no grid sync needed)

  // ---------------- decoder: 64 autoregressive steps ----------------
  for (int s = 0; s < TDEC; ++s) {
    const int rgen = TENC + s, wgen = rgen + 1;
    const size_t roff = (size_t)(ring ? rgen : (rgen & 1)) * GEN;
    const size_t woff = (size_t)(ring ? wgen : (wgen & 1)) * GEN;
    f16x8 pa0[16], pa1[16];
    gemm_prefetch(P.h16 + roff, ring, w, l15, quad, pa0, pa1);
    if (t < 256) fcp[t] = 0.f;
    for (int e = t; e < 2048; e += NTHR) {      // gbuf = dbias only (rank-4 later)
      int b = e >> 5, n = e & 31;
      gbuf[b * 36 + n] = bsm[n];
    }
    ldsbar();
    waitpa();
    gemm_compute<true>(wlds, fcT, gbuf, fcp, w, l15, quad, pa0, pa1);
    ldsbar();
    if (t < NBAT) {          // xv = input for this step = fc(h_prev) (or x0 at s==0)
      float4 o;
      if (s == 0) {
        o = ((const float4*)P.x)[t * TENC + (P.lengths[t] - 1)];
      } else {
        float4 p = ((const float4*)fcp)[t];
        o.x = fcb.x + p.x; o.y = fcb.y + p.y; o.z = fcb.z + p.z; o.w = fcb.w + p.w;
      }
      ((float4*)xv)[t] = o;
      if (s >= 1 && bid == s)                   // rotating prediction writer
        ((float4*)P.dst)[t * TDEC + (s - 1)] = o;
    }
    ldsbar();
    for (int e = t; e < 2048; e += NTHR) {      // gbuf += rank-4(xv, M1)
      int b = e >> 5, n = e & 31;
      float4 wv = ((const float4*)wsm)[n];
      const float* xb = xv + b * 4;
      gbuf[b * 36 + n] += xb[0] * wv.x + xb[1] * wv.y + xb[2] * wv.z + xb[3] * wv.w;
    }
    ldsbar();
    {
      float gi = gbuf[bb * 36 + jj],      gf = gbuf[bb * 36 + 8 + jj];
      float gg = gbuf[bb * 36 + 16 + jj], go = gbuf[bb * 36 + 24 + jj];
      float ii = 1.f / (1.f + expf(-gi));
      float ff = 1.f / (1.f + expf(-gf));
      float g  = tanhf(gg);
      float oo = 1.f / (1.f + expf(-go));
      creg = ff * creg + ii * g;
      hreg = oo * tanhf(creg);
      unsigned hv = (unsigned)__builtin_bit_cast(unsigned short, (f16)hreg);
      unsigned v1 = __shfl_down(hv, 1), v2 = __shfl_down(hv, 2), v3 = __shfl_down(hv, 3);
      if ((t & 3) == 0) {
        unsigned long long pk = (unsigned long long)hv | ((unsigned long long)v1 << 16)
                              | ((unsigned long long)v2 << 32) | ((unsigned long long)v3 << 48);
        astore_u64((float*)(P.h16 + woff + (size_t)bb * HID + bid * 8 + (jj & 4)), pk);
      }
    }
    gbar(P.bar, target, bid);
  }

  // ---------------- epilogue: out(63) = fc(H_63) by block 0 ----------------
  if (bid == 0) {
    if (t < 256) fcp[t] = 0.f;
    f16x8 pa0[16], pa1[16];
    gemm_prefetch(P.h16 + (size_t)(ring ? (TENC + TDEC) : ((TENC + TDEC) & 1)) * GEN,
                  ring, w, l15, quad, pa0, pa1);
    ldsbar();
    waitpa();
    fc_compute(fcT, fcp, w, l15, quad, pa0, pa1);
    ldsbar();
    if (t < NBAT) {
      float4 p = ((const float4*)fcp)[t];
      float4 o;
      o.x = fcb.x + p.x; o.y = fcb.y + p.y; o.z = fcb.z + p.z; o.w = fcb.w + p.w;
      ((float4*)P.dst)[t * TDEC + 63] = o;       // predictions[b][63]
      ((float4*)(P.dst + 16384))[t]   = o;       // out
    }
  }
  P.dst[16640  + (size_t)bb * HID + jglob] = hreg;   // h
  P.dst[147712 + (size_t)bb * HID + jglob] = creg;   // c
}

extern "C" void kernel_launch(void* const* d_in, const int* in_sizes, int n_in,
                              void* d_out, int out_size, void* d_ws, size_t ws_size,
                              hipStream_t stream) {
  (void)in_sizes; (void)n_in; (void)out_size;
  Params P;
  P.x        = (const float*)d_in[0];
  P.lengths  = (const int*)  d_in[1];
  // d_in[2] = target_len (constant 64)
  P.enc_Wih  = (const float*)d_in[3];
  P.enc_Whh  = (const float*)d_in[4];
  P.enc_bih  = (const float*)d_in[5];
  P.enc_bhh  = (const float*)d_in[6];
  P.emb_W    = (const float*)d_in[7];
  P.emb_b    = (const float*)d_in[8];
  P.dec_Wih  = (const float*)d_in[9];
  P.dec_Whh  = (const float*)d_in[10];
  P.dec_bih  = (const float*)d_in[11];
  P.dec_bhh  = (const float*)d_in[12];
  P.fc_W     = (const float*)d_in[13];
  P.fc_b     = (const float*)d_in[14];
  P.dst      = (float*)d_out;

  char* ws = (char*)d_ws;
  const size_t slot = (size_t)NBAT * HID * sizeof(_Float16);   // 262144 B per generation
  const size_t ring_bytes = (size_t)(TENC + TDEC + 1) * slot;  // 193 slots = 50,593,792 B
  int ring = (ws_size >= ring_bytes + 16384) ? 1 : 0;
  P.h16  = (f16*)ws;
  P.bar  = (unsigned*)(ws + (ring ? ring_bytes : 2 * slot));
  P.ring = ring;

  hipMemsetAsync(P.bar, 0, 12288, stream);           // ws is poisoned 0xAA

  hipFuncSetAttribute((const void*)lstm_persistent,
                      hipFuncAttributeMaxDynamicSharedMemorySize, SMEM_BYTES);
  void* args[] = { &P };
  hipLaunchCooperativeKernel((const void*)lstm_persistent, dim3(NBLK), dim3(NTHR),
                             args, SMEM_BYTES, stream);
}

// Round 4
// 4047.919 us; speedup vs baseline: 1.1568x; 1.0627x over previous
//
#include <hip/hip_runtime.h>
#include <hip/hip_fp16.h>

// ---------------------------------------------------------------------------
// LSTM position predictor, persistent cooperative kernel. Round 7.
//   Rounds 2-6 (24.4 -> 21.8 us/step): four different sync/cache schemes all
//   land within 12% -> the invariant cost is the h all-gather TRANSPORT
//   (scattered 8B writes, 4KB-strided reads) and the 2-hop barrier, not the
//   cache protocol. Round 7 restructures all three:
//   1) TILED h16 ring layout [gen][colgrp=bid][batch][8]: producer writes its
//      1KB as 16 FULL 64B lines (vs 128 scattered 8B partials); consumer
//      A-fragment reads become 256B contiguous per 16 lanes (vs 16 distinct
//      lines per 16 lanes). Same bytes, ~4x fewer line transactions each way.
//   2) DATAFLOW sync (no global barrier, no release hop): each wave polls
//      only its 64 K-slice producer blocks (bar slots kq*64+l, 4 lines) and
//      prefetches as soon as ITS slice is ready. Arrival = one sc0 sc1 level
//      store after the h-store drain. Union of the 8 waves' slices = all 256
//      blocks, which also gives the 2-buffer fallback its write-after-read
//      backpressure (safe in both modes).
//   3) Rank-4 input term folded into the gate phase (gbuf init = bias only;
//      gate thread adds 4 dot4s) - deletes one 2048-elem LDS pass + barrier
//      per step and the decoder's entire second gbuf pass.
//   Kept from r6: write-once ring (193 gens, no steady-state inv), one-time
//   entry buffer_inv, fp16 weights persistent in LDS, fused fc GEMM, folded
//   dec_Wih, LDS-only intra-step barriers, deep register prefetch.
// ---------------------------------------------------------------------------

#define HID   2048
#define NBAT  64
#define TENC  128
#define TDEC  64
#define NBLK  256
#define NTHR  512
#define WROW  2056   // f16 per LDS weight row (+8 pad, 16B aligned)
#define FROW  2056   // f16 per fcT row

typedef _Float16 f16;
typedef _Float16 f16x8 __attribute__((ext_vector_type(8)));
typedef _Float16 f16x4 __attribute__((ext_vector_type(4)));
typedef float    f32x4v __attribute__((ext_vector_type(4)));

// LDS layout (bytes):
//   0      : wlds  32 x 2056 f16      = 131584
//   131584 : gbuf  [64][36] f32       =   9216
//   140800 : xv    [64][4]  f32       =   1024
//   141824 : wsm   [32][4]  f32       =    512
//   142336 : bsm   [32]     f32       =    128
//   142464 : fcp   [64][4]  f32       =   1024
//   143488 : fcT   [4][2056] f16      =  16448
#define SMEM_BYTES 159936

#define DOT4(a,b) ((a).x*(b).x + (a).y*(b).y + (a).z*(b).z + (a).w*(b).w)

struct Params {
  const float* x; const int* lengths;
  const float* enc_Wih; const float* enc_Whh; const float* enc_bih; const float* enc_bhh;
  const float* emb_W; const float* emb_b;
  const float* dec_Wih; const float* dec_Whh; const float* dec_bih; const float* dec_bhh;
  const float* fc_W; const float* fc_b;
  float* dst;        // 278784 floats: preds[64][64][4], out[64][4], h[64][2048], c[64][2048]
  f16* h16;          // ws: ring of 193 gen buffers (or 2 in fallback), tiled [gen][grp][batch][8]
  unsigned* bar;     // ws: per-block level slots [0..255]
  int ring;          // 1 = write-once ring (cached reads); 0 = 2-buf bypass loads
};

__device__ __forceinline__ void astore_u64(f16* p, unsigned long long v) {
  __hip_atomic_store((unsigned long long*)p, v, __ATOMIC_RELAXED, __HIP_MEMORY_SCOPE_AGENT);
}
__device__ __forceinline__ f16x8 bload_f16x8(const f16* p) {   // IF-bypass load, left in flight
  f16x8 r;
  asm volatile("global_load_dwordx4 %0, %1, off sc0 sc1" : "=v"(r) : "v"(p));
  return r;
}
// Block-local barrier that drains ONLY LDS (keeps vmem prefetch in flight).
__device__ __forceinline__ void ldsbar() {
  asm volatile("s_waitcnt lgkmcnt(0)" ::: "memory");
  __builtin_amdgcn_s_barrier();
}
// Drain prefetch before MFMA use; fence against MFMA hoisting (rule #18).
__device__ __forceinline__ void waitpa() {
  asm volatile("s_waitcnt vmcnt(0)" ::: "memory");
  __builtin_amdgcn_sched_barrier(0);
}

// --- dataflow sync --------------------------------------------------------
// Wave-slice wait: lane l polls producer block (kq*64 + l)'s level slot.
// The wave proceeds when all its 64 producers reached `level`.
__device__ __forceinline__ void wait_slice(const unsigned* bar, int kq, int l,
                                           unsigned level) {
  const unsigned* slot = bar + (kq << 6) + l;
  for (;;) {
    unsigned v;
    asm volatile("global_load_dword %0, %1, off sc0 sc1\n\ts_waitcnt vmcnt(0)"
                 : "=v"(v) : "v"(slot) : "memory");
    if (v >= level) break;
    __builtin_amdgcn_s_sleep(1);
  }
}
// Arrival: publish this block's level (call from t==0 AFTER __syncthreads,
// which has drained every wave's h16 stores to the coherent point).
__device__ __forceinline__ void arrive(unsigned* bar, int bid, unsigned level) {
  asm volatile("s_waitcnt vmcnt(0)" ::: "memory");
  asm volatile("global_store_dword %0, %1, off sc0 sc1\n\ts_waitcnt vmcnt(0)"
               :: "v"(bar + bid), "v"(level) : "memory");
}

// Convert this block's 32 gate rows of W (fp32 [8192][2048]) into LDS fp16.
__device__ __forceinline__ void fill_weights(const float* __restrict__ W, int bid,
                                             f16* wlds, int w, int l) {
  #pragma unroll
  for (int rr = 0; rr < 4; ++rr) {
    int r  = w * 4 + rr;
    int gr = ((r >> 3) << 11) + bid * 8 + (r & 7);
    const float4* src = (const float4*)(W + (size_t)gr * HID);
    f16* dst = wlds + (size_t)r * WROW;
    #pragma unroll
    for (int it = 0; it < 8; ++it) {
      float4 v = src[it * 64 + l];
      f16x4 h4; h4[0] = (f16)v.x; h4[1] = (f16)v.y; h4[2] = (f16)v.z; h4[3] = (f16)v.w;
      *(f16x4*)(dst + (it * 64 + l) * 4) = h4;
    }
  }
}

// Issue ALL h16 A-fragment loads for this wave into registers (tiled layout).
// Tile addr for (col c, batch b) = (c>>3)*512 + b*8 + (c&7); wave (mh,kq),
// lane (l15,quad), chunk ch reads cols kq*512+quad*8+ch*32 .. +8 for batches
// mh*32+l15 (pa0) and +16 (pa1): grp = kq*64+quad+ch*4 -> contiguous 16B, and
// 16 consecutive l15 lanes form one contiguous 256B run.
__device__ __forceinline__ void gemm_prefetch(const f16* __restrict__ hp, int ring,
                                              int w, int l15, int quad,
                                              f16x8* pa0, f16x8* pa1) {
  const int mh = w & 1, kq = w >> 1;
  const f16* A0 = hp + ((size_t)(kq * 64 + quad)) * 512 + (size_t)(mh * 32 + l15) * 8;
  if (ring) {           // write-once ring: cached loads, L2 multicast per XCD
    #pragma unroll
    for (int ch = 0; ch < 16; ++ch) {
      pa0[ch] = *(const f16x8*)(A0 + ch * 2048);
      pa1[ch] = *(const f16x8*)(A0 + ch * 2048 + 128);
    }
  } else {              // fallback: IF-bypass loads (no stale-L2 hazard)
    #pragma unroll
    for (int ch = 0; ch < 16; ++ch) {
      pa0[ch] = bload_f16x8(A0 + ch * 2048);
      pa1[ch] = bload_f16x8(A0 + ch * 2048 + 128);
    }
  }
}

// fc partial: out[b][d] += sum_k h[b][k] * fcW[d][k] over this wave's fragment.
__device__ __forceinline__ void fc_compute(const f16* fcT, float* fcp,
                                           int w, int l15, int quad,
                                           const f16x8* pa0, const f16x8* pa1) {
  const int mh = w & 1, kq = w >> 1;
  f32x4v f0 = {0.f, 0.f, 0.f, 0.f}, f1 = f0;
  const f16* BF = fcT + (size_t)l15 * FROW + kq * 512 + quad * 8;
  #pragma unroll
  for (int ch = 0; ch < 16; ++ch) {
    f16x8 vbF = {};
    if (l15 < 4) vbF = *(const f16x8*)(BF + ch * 32);
    f0 = __builtin_amdgcn_mfma_f32_16x16x32_f16(pa0[ch], vbF, f0, 0, 0, 0);
    f1 = __builtin_amdgcn_mfma_f32_16x16x32_f16(pa1[ch], vbF, f1, 0, 0, 0);
  }
  if (l15 < 4) {
    const int brow = mh * 32 + quad * 4;
    #pragma unroll
    for (int r = 0; r < 4; ++r) {
      unsafeAtomicAdd(&fcp[(brow + r) * 4 + l15],      f0[r]);
      unsafeAtomicAdd(&fcp[(brow + 16 + r) * 4 + l15], f1[r]);
    }
  }
}

// gates += h @ Whh.T for this block's 32 gate rows; optional fused fc partial.
template<bool FC>
__device__ __forceinline__ void gemm_compute(const f16* wlds, const f16* fcT,
                                             float* gbuf, float* fcp,
                                             int w, int l15, int quad,
                                             const f16x8* pa0, const f16x8* pa1) {
  const int mh = w & 1, kq = w >> 1;
  f32x4v a00 = {0.f, 0.f, 0.f, 0.f}, a01 = a00, a10 = a00, a11 = a00;
  const f16* B0 = wlds + (size_t)l15 * WROW + kq * 512 + quad * 8;
  const f16* B1 = B0 + (size_t)16 * WROW;
  #pragma unroll
  for (int ch = 0; ch < 16; ++ch) {
    f16x8 vb0 = *(const f16x8*)(B0 + ch * 32);
    f16x8 vb1 = *(const f16x8*)(B1 + ch * 32);
    a00 = __builtin_amdgcn_mfma_f32_16x16x32_f16(pa0[ch], vb0, a00, 0, 0, 0);
    a01 = __builtin_amdgcn_mfma_f32_16x16x32_f16(pa0[ch], vb1, a01, 0, 0, 0);
    a10 = __builtin_amdgcn_mfma_f32_16x16x32_f16(pa1[ch], vb0, a10, 0, 0, 0);
    a11 = __builtin_amdgcn_mfma_f32_16x16x32_f16(pa1[ch], vb1, a11, 0, 0, 0);
  }
  const int brow = mh * 32 + quad * 4;
  #pragma unroll
  for (int r = 0; r < 4; ++r) {
    unsafeAtomicAdd(&gbuf[(brow + r)      * 36 +      l15], a00[r]);
    unsafeAtomicAdd(&gbuf[(brow + r)      * 36 + 16 + l15], a01[r]);
    unsafeAtomicAdd(&gbuf[(brow + 16 + r) * 36 +      l15], a10[r]);
    unsafeAtomicAdd(&gbuf[(brow + 16 + r) * 36 + 16 + l15], a11[r]);
  }
  if (FC) fc_compute(fcT, fcp, w, l15, quad, pa0, pa1);
}

extern "C" __global__ void __launch_bounds__(NTHR, 2)
lstm_persistent(Params P) {
  extern __shared__ char smem[];
  f16*   wlds = (f16*)smem;
  float* gbuf = (float*)(smem + 131584);
  float* xv   = (float*)(smem + 140800);
  float* wsm  = (float*)(smem + 141824);
  float* bsm  = (float*)(smem + 142336);
  float* fcp  = (float*)(smem + 142464);
  f16*   fcT  = (f16*)(smem + 143488);

  const int t    = threadIdx.x;
  const int bid  = blockIdx.x;
  const int w    = t >> 6;
  const int l    = t & 63;
  const int l15  = l & 15;
  const int quad = l >> 4;
  const int kq   = w >> 1;
  const int bb   = t >> 3;
  const int jj   = t & 7;
  const int jglob = bid * 8 + jj;
  const int ring = P.ring;
  const size_t GEN = (size_t)NBAT * HID;   // f16 per generation buffer

  // ---------------- one-time cache scrub (cross-dispatch stale lines) ------
  // Safe (r6-proven): no dirty lines exist at entry; each block's inv is in
  // program order before any of its ring reads; clean-line drops are benign.
  if (t == 0)
    asm volatile("s_waitcnt vmcnt(0)\n\tbuffer_inv sc0 sc1\n\ts_waitcnt vmcnt(0)" ::: "memory");
  __syncthreads();

  // ---------------- setup (block-local) ----------------
  if (t < 32) {
    int r = t, gr = ((r >> 3) << 11) + bid * 8 + (r & 7);
    ((float4*)wsm)[r] = ((const float4*)P.enc_Wih)[gr];
    bsm[r] = P.enc_bih[gr] + P.enc_bhh[gr];
  }
  fill_weights(P.enc_Whh, bid, wlds, w, l);

  const int len_b = P.lengths[bb];
  const float4 fcb = ((const float4*)P.fc_b)[0];
  float hreg = 0.f, creg = 0.f;

  // ---------------- encoder: 128 masked steps ----------------
  for (int ts = 0; ts < TENC; ++ts) {
    const size_t roff = (size_t)(ring ? ts : (ts & 1)) * GEN;
    const size_t woff = (size_t)(ring ? (ts + 1) : ((ts + 1) & 1)) * GEN;
    if (ts > 0) wait_slice(P.bar, kq, l, (unsigned)ts);   // per-wave K-slice wait
    f16x8 pa0[16], pa1[16];
    if (ts > 0) gemm_prefetch(P.h16 + roff, ring, w, l15, quad, pa0, pa1);
    if (t < NBAT) ((float4*)xv)[t] = ((const float4*)P.x)[t * TENC + ts];
    for (int e = t; e < 2048; e += NTHR) {       // gbuf = bias broadcast only
      int b = e >> 5, n = e & 31;
      gbuf[b * 36 + n] = bsm[n];
    }
    ldsbar();
    if (ts > 0) { waitpa(); gemm_compute<false>(wlds, fcT, gbuf, fcp, w, l15, quad, pa0, pa1); }
    ldsbar();
    {
      const float4 xb  = ((const float4*)xv)[bb];
      const float4 wi4 = ((const float4*)wsm)[jj];
      const float4 wf4 = ((const float4*)wsm)[8 + jj];
      const float4 wg4 = ((const float4*)wsm)[16 + jj];
      const float4 wo4 = ((const float4*)wsm)[24 + jj];
      float gi = gbuf[bb * 36 + jj]      + DOT4(xb, wi4);
      float gf = gbuf[bb * 36 + 8 + jj]  + DOT4(xb, wf4);
      float gg = gbuf[bb * 36 + 16 + jj] + DOT4(xb, wg4);
      float go = gbuf[bb * 36 + 24 + jj] + DOT4(xb, wo4);
      float ii = 1.f / (1.f + expf(-gi));
      float ff = 1.f / (1.f + expf(-gf));
      float g  = tanhf(gg);
      float oo = 1.f / (1.f + expf(-go));
      float cn = ff * creg + ii * g;
      float hn = oo * tanhf(cn);
      if (ts < len_b) { creg = cn; hreg = hn; }   // packed-sequence freeze
      unsigned hv = (unsigned)__builtin_bit_cast(unsigned short, (f16)hreg);
      unsigned v1 = __shfl_down(hv, 1), v2 = __shfl_down(hv, 2), v3 = __shfl_down(hv, 3);
      if ((t & 3) == 0) {   // tiled write: [grp=bid][batch=bb][8] -> full lines
        unsigned long long pk = (unsigned long long)hv | ((unsigned long long)v1 << 16)
                              | ((unsigned long long)v2 << 32) | ((unsigned long long)v3 << 48);
        astore_u64(P.h16 + woff + (size_t)bid * 512 + (size_t)bb * 8 + (jj & 4), pk);
      }
    }
    __syncthreads();                              // drains h16 stores (all waves)
    if (t == 0) arrive(P.bar, bid, (unsigned)(ts + 1));
  }

  // ------- transition (block-local; overlaps other XCDs' tails) -------
  fill_weights(P.dec_Whh, bid, wlds, w, l);
  #pragma unroll
  for (int rr = 0; rr < 4; ++rr) {       // M1 = dec_Wih@emb_W straight into LDS
    int r = w * 4 + rr, gr = ((r >> 3) << 11) + bid * 8 + (r & 7);
    const float* wr = P.dec_Wih + (size_t)gr * HID;
    float a0 = 0.f, a1 = 0.f, a2 = 0.f, a3 = 0.f, ab = 0.f;
    for (int k = l; k < HID; k += 64) {
      float wv = wr[k];
      float4 e = ((const float4*)P.emb_W)[k];
      a0 += wv * e.x; a1 += wv * e.y; a2 += wv * e.z; a3 += wv * e.w;
      ab += wv * P.emb_b[k];
    }
    #pragma unroll
    for (int off = 32; off > 0; off >>= 1) {
      a0 += __shfl_xor(a0, off); a1 += __shfl_xor(a1, off);
      a2 += __shfl_xor(a2, off); a3 += __shfl_xor(a3, off);
      ab += __shfl_xor(ab, off);
    }
    if (l == 0) {
      wsm[r * 4 + 0] = a0; wsm[r * 4 + 1] = a1; wsm[r * 4 + 2] = a2; wsm[r * 4 + 3] = a3;
      bsm[r] = ab + P.dec_bih[gr] + P.dec_bhh[gr];
    }
  }
  for (int i = t; i < 2048; i += NTHR) {   // fcT[d][k] = (f16)fc_W[d][k]
    int d = i >> 9, k4 = i & 511;
    float4 v = ((const float4*)P.fc_W)[i];
    f16x4 h4; h4[0] = (f16)v.x; h4[1] = (f16)v.y; h4[2] = (f16)v.z; h4[3] = (f16)v.w;
    *(f16x4*)(fcT + (size_t)d * FROW + k4 * 4) = h4;
  }
  ldsbar();   // block-local: wlds/wsm/bsm/fcT visible

  // ---------------- decoder: 64 autoregressive steps ----------------
  for (int s = 0; s < TDEC; ++s) {
    const int rgen = TENC + s, wgen = rgen + 1;
    const size_t roff = (size_t)(ring ? rgen : (rgen & 1)) * GEN;
    const size_t woff = (size_t)(ring ? wgen : (wgen & 1)) * GEN;
    wait_slice(P.bar, kq, l, (unsigned)rgen);
    f16x8 pa0[16], pa1[16];
    gemm_prefetch(P.h16 + roff, ring, w, l15, quad, pa0, pa1);
    if (t < 256) fcp[t] = 0.f;
    for (int e = t; e < 2048; e += NTHR) {      // gbuf = dbias broadcast only
      int b = e >> 5, n = e & 31;
      gbuf[b * 36 + n] = bsm[n];
    }
    ldsbar();
    waitpa();
    gemm_compute<true>(wlds, fcT, gbuf, fcp, w, l15, quad, pa0, pa1);
    ldsbar();
    if (t < NBAT) {          // xv = input for this step = fc(h_prev) (or x0 at s==0)
      float4 o;
      if (s == 0) {
        o = ((const float4*)P.x)[t * TENC + (P.lengths[t] - 1)];
      } else {
        float4 p = ((const float4*)fcp)[t];
        o.x = fcb.x + p.x; o.y = fcb.y + p.y; o.z = fcb.z + p.z; o.w = fcb.w + p.w;
      }
      ((float4*)xv)[t] = o;
      if (s >= 1 && bid == s)                   // rotating prediction writer
        ((float4*)P.dst)[t * TDEC + (s - 1)] = o;
    }
    ldsbar();
    {
      const float4 xb  = ((const float4*)xv)[bb];
      const float4 wi4 = ((const float4*)wsm)[jj];
      const float4 wf4 = ((const float4*)wsm)[8 + jj];
      const float4 wg4 = ((const float4*)wsm)[16 + jj];
      const float4 wo4 = ((const float4*)wsm)[24 + jj];
      float gi = gbuf[bb * 36 + jj]      + DOT4(xb, wi4);
      float gf = gbuf[bb * 36 + 8 + jj]  + DOT4(xb, wf4);
      float gg = gbuf[bb * 36 + 16 + jj] + DOT4(xb, wg4);
      float go = gbuf[bb * 36 + 24 + jj] + DOT4(xb, wo4);
      float ii = 1.f / (1.f + expf(-gi));
      float ff = 1.f / (1.f + expf(-gf));
      float g  = tanhf(gg);
      float oo = 1.f / (1.f + expf(-go));
      creg = ff * creg + ii * g;
      hreg = oo * tanhf(creg);
      unsigned hv = (unsigned)__builtin_bit_cast(unsigned short, (f16)hreg);
      unsigned v1 = __shfl_down(hv, 1), v2 = __shfl_down(hv, 2), v3 = __shfl_down(hv, 3);
      if ((t & 3) == 0) {
        unsigned long long pk = (unsigned long long)hv | ((unsigned long long)v1 << 16)
                              | ((unsigned long long)v2 << 32) | ((unsigned long long)v3 << 48);
        astore_u64(P.h16 + woff + (size_t)bid * 512 + (size_t)bb * 8 + (jj & 4), pk);
      }
    }
    __syncthreads();
    if (t == 0) arrive(P.bar, bid, (unsigned)wgen);
  }

  // ---------------- epilogue: out(63) = fc(H_63) by block 0 ----------------
  if (bid == 0) {
    wait_slice(P.bar, kq, l, (unsigned)(TENC + TDEC));
    if (t < 256) fcp[t] = 0.f;
    f16x8 pa0[16], pa1[16];
    gemm_prefetch(P.h16 + (size_t)(ring ? (TENC + TDEC) : ((TENC + TDEC) & 1)) * GEN,
                  ring, w, l15, quad, pa0, pa1);
    ldsbar();
    waitpa();
    fc_compute(fcT, fcp, w, l15, quad, pa0, pa1);
    ldsbar();
    if (t < NBAT) {
      float4 p = ((const float4*)fcp)[t];
      float4 o;
      o.x = fcb.x + p.x; o.y = fcb.y + p.y; o.z = fcb.z + p.z; o.w = fcb.w + p.w;
      ((float4*)P.dst)[t * TDEC + 63] = o;       // predictions[b][63]
      ((float4*)(P.dst + 16384))[t]   = o;       // out
    }
  }
  P.dst[16640  + (size_t)bb * HID + jglob] = hreg;   // h
  P.dst[147712 + (size_t)bb * HID + jglob] = creg;   // c
}

extern "C" void kernel_launch(void* const* d_in, const int* in_sizes, int n_in,
                              void* d_out, int out_size, void* d_ws, size_t ws_size,
                              hipStream_t stream) {
  (void)in_sizes; (void)n_in; (void)out_size;
  Params P;
  P.x        = (const float*)d_in[0];
  P.lengths  = (const int*)  d_in[1];
  // d_in[2] = target_len (constant 64)
  P.enc_Wih  = (const float*)d_in[3];
  P.enc_Whh  = (const float*)d_in[4];
  P.enc_bih  = (const float*)d_in[5];
  P.enc_bhh  = (const float*)d_in[6];
  P.emb_W    = (const float*)d_in[7];
  P.emb_b    = (const float*)d_in[8];
  P.dec_Wih  = (const float*)d_in[9];
  P.dec_Whh  = (const float*)d_in[10];
  P.dec_bih  = (const float*)d_in[11];
  P.dec_bhh  = (const float*)d_in[12];
  P.fc_W     = (const float*)d_in[13];
  P.fc_b     = (const float*)d_in[14];
  P.dst      = (float*)d_out;

  char* ws = (char*)d_ws;
  const size_t slot = (size_t)NBAT * HID * sizeof(_Float16);   // 262144 B per generation
  const size_t ring_bytes = (size_t)(TENC + TDEC + 1) * slot;  // 193 slots = 50,593,792 B
  int ring = (ws_size >= ring_bytes + 16384) ? 1 : 0;
  P.h16  = (f16*)ws;
  P.bar  = (unsigned*)(ws + (ring ? ring_bytes : 2 * slot));
  P.ring = ring;

  hipMemsetAsync(P.bar, 0, 12288, stream);           // ws is poisoned 0xAA

  hipFuncSetAttribute((const void*)lstm_persistent,
                      hipFuncAttributeMaxDynamicSharedMemorySize, SMEM_BYTES);
  void* args[] = { &P };
  hipLaunchCooperativeKernel((const void*)lstm_persistent, dim3(NBLK), dim3(NTHR),
                             args, SMEM_BYTES, stream);
}

// Round 7
// 3490.782 us; speedup vs baseline: 1.3415x; 1.1596x over previous
//
#include <hip/hip_runtime.h>
#include <hip/hip_fp16.h>

// ---------------------------------------------------------------------------
// LSTM position predictor, persistent cooperative kernel. Round 10.
//   r9 failed correctness (intermittent absmax up to 468): the ONLY
//   coherence-touching delta was __builtin_nontemporal_load on the h stream.
//   nt loads can bypass the cache level holding the producer's sc1
//   write-through data -> stale reads. LESSON: never mix nt loads with
//   flag-ordered producer/consumer data. The other r9 delta (dropping the
//   full vmcnt(0) drain for ring-mode loads) is register-dataflow-safe:
//   plain visible loads get correct compiler-inserted per-use vmcnt(N).
//   ROUND 10 = r7 (passed, 4048us) + the two SAFE r9 deltas only:
//   1) Ring-mode h loads: plain cached loads (r7-identical path), but NO
//      waitpa() drain -> compiler emits fine-grained vmcnt(N); MFMA overlaps
//      the tail of the 512KB/CU/step h-fill instead of waiting for all of it.
//      (Fallback asm-bypass path keeps its mandatory drain, rule #18.)
//   2) Pre-wait hoisting: gbuf bias init / xv stage / fcp zero run BEFORE
//      the dataflow wait (h-independent, block-local, proven structure).
//   Kept from r7: tiled write-once h16 ring [gen][grp=bid][batch][8] (no
//   steady-state inv), one-time entry buffer_inv, per-wave K-slice dataflow
//   sync (poll and store at the SAME sc0 sc1 coherence point), fused fc
//   GEMM, folded rank-4 input, fp16 weights persistent in LDS, LDS-only
//   intra-step barriers.
// ---------------------------------------------------------------------------

#define HID   2048
#define NBAT  64
#define TENC  128
#define TDEC  64
#define NBLK  256
#define NTHR  512
#define WROW  2056   // f16 per LDS weight row (+8 pad, 16B aligned)
#define FROW  2056   // f16 per fcT row

typedef _Float16 f16;
typedef _Float16 f16x8 __attribute__((ext_vector_type(8)));
typedef _Float16 f16x4 __attribute__((ext_vector_type(4)));
typedef float    f32x4v __attribute__((ext_vector_type(4)));

// LDS layout (bytes):
//   0      : wlds  32 x 2056 f16      = 131584
//   131584 : gbuf  [64][36] f32       =   9216
//   140800 : xv    [64][4]  f32       =   1024
//   141824 : wsm   [32][4]  f32       =    512
//   142336 : bsm   [32]     f32       =    128
//   142464 : fcp   [64][4]  f32       =   1024
//   143488 : fcT   [4][2056] f16      =  16448
#define SMEM_BYTES 159936

#define DOT4(a,b) ((a).x*(b).x + (a).y*(b).y + (a).z*(b).z + (a).w*(b).w)

struct Params {
  const float* x; const int* lengths;
  const float* enc_Wih; const float* enc_Whh; const float* enc_bih; const float* enc_bhh;
  const float* emb_W; const float* emb_b;
  const float* dec_Wih; const float* dec_Whh; const float* dec_bih; const float* dec_bhh;
  const float* fc_W; const float* fc_b;
  float* dst;        // 278784 floats: preds[64][64][4], out[64][4], h[64][2048], c[64][2048]
  f16* h16;          // ws: ring of 193 gen buffers (or 2 in fallback), tiled [gen][grp][batch][8]
  unsigned* bar;     // ws: per-block level slots [0..255]
  int ring;          // 1 = write-once ring (cached reads); 0 = 2-buf bypass loads
};

__device__ __forceinline__ void astore_u64(f16* p, unsigned long long v) {
  __hip_atomic_store((unsigned long long*)p, v, __ATOMIC_RELAXED, __HIP_MEMORY_SCOPE_AGENT);
}
__device__ __forceinline__ f16x8 bload_f16x8(const f16* p) {   // IF-bypass load, left in flight
  f16x8 r;
  asm volatile("global_load_dwordx4 %0, %1, off sc0 sc1" : "=v"(r) : "v"(p));
  return r;
}
// Block-local barrier that drains ONLY LDS (keeps vmem prefetch in flight).
__device__ __forceinline__ void ldsbar() {
  asm volatile("s_waitcnt lgkmcnt(0)" ::: "memory");
  __builtin_amdgcn_s_barrier();
}
// Full drain + scheduling fence (rule #18) - asm-load path and epilogue only.
__device__ __forceinline__ void waitpa() {
  asm volatile("s_waitcnt vmcnt(0)" ::: "memory");
  __builtin_amdgcn_sched_barrier(0);
}

// --- dataflow sync (r7-proven; poll and store at the SAME coherence point) -
// Wave-slice wait: lane l polls producer block (kq*64 + l)'s level slot.
__device__ __forceinline__ void wait_slice(const unsigned* bar, int kq, int l,
                                           unsigned level) {
  const unsigned* slot = bar + (kq << 6) + l;
  for (;;) {
    unsigned v;
    asm volatile("global_load_dword %0, %1, off sc0 sc1\n\ts_waitcnt vmcnt(0)"
                 : "=v"(v) : "v"(slot) : "memory");
    if (v >= level) break;
    __builtin_amdgcn_s_sleep(1);
  }
}
// Arrival: publish this block's level (t==0, AFTER __syncthreads drained all
// waves' h16 stores).
__device__ __forceinline__ void arrive(unsigned* bar, int bid, unsigned level) {
  asm volatile("s_waitcnt vmcnt(0)" ::: "memory");
  asm volatile("global_store_dword %0, %1, off sc0 sc1\n\ts_waitcnt vmcnt(0)"
               :: "v"(bar + bid), "v"(level) : "memory");
}

// Convert this block's 32 gate rows of W (fp32 [8192][2048]) into LDS fp16.
__device__ __forceinline__ void fill_weights(const float* __restrict__ W, int bid,
                                             f16* wlds, int w, int l) {
  #pragma unroll
  for (int rr = 0; rr < 4; ++rr) {
    int r  = w * 4 + rr;
    int gr = ((r >> 3) << 11) + bid * 8 + (r & 7);
    const float4* src = (const float4*)(W + (size_t)gr * HID);
    f16* dst = wlds + (size_t)r * WROW;
    #pragma unroll
    for (int it = 0; it < 8; ++it) {
      float4 v = src[it * 64 + l];
      f16x4 h4; h4[0] = (f16)v.x; h4[1] = (f16)v.y; h4[2] = (f16)v.z; h4[3] = (f16)v.w;
      *(f16x4*)(dst + (it * 64 + l) * 4) = h4;
    }
  }
}

// Issue ALL h16 A-fragment loads for this wave (tiled layout).
// Ring mode: plain cached loads (coherent with the sc1-drained producer
// stores after the flag), compiler inserts fine-grained per-use vmcnt(N).
__device__ __forceinline__ void gemm_prefetch(const f16* __restrict__ hp, int ring,
                                              int w, int l15, int quad,
                                              f16x8* pa0, f16x8* pa1) {
  const int mh = w & 1, kq = w >> 1;
  const f16* A0 = hp + ((size_t)(kq * 64 + quad)) * 512 + (size_t)(mh * 32 + l15) * 8;
  if (ring) {
    #pragma unroll
    for (int ch = 0; ch < 16; ++ch) {
      pa0[ch] = *(const f16x8*)(A0 + ch * 2048);
      pa1[ch] = *(const f16x8*)(A0 + ch * 2048 + 128);
    }
  } else {              // fallback: IF-bypass asm loads (caller must waitpa())
    #pragma unroll
    for (int ch = 0; ch < 16; ++ch) {
      pa0[ch] = bload_f16x8(A0 + ch * 2048);
      pa1[ch] = bload_f16x8(A0 + ch * 2048 + 128);
    }
  }
}

// fc partial: out[b][d] += sum_k h[b][k] * fcW[d][k] over this wave's fragment.
__device__ __forceinline__ void fc_compute(const f16* fcT, float* fcp,
                                           int w, int l15, int quad,
                                           const f16x8* pa0, const f16x8* pa1) {
  const int mh = w & 1, kq = w >> 1;
  f32x4v f0 = {0.f, 0.f, 0.f, 0.f}, f1 = f0;
  const f16* BF = fcT + (size_t)l15 * FROW + kq * 512 + quad * 8;
  #pragma unroll
  for (int ch = 0; ch < 16; ++ch) {
    f16x8 vbF = {};
    if (l15 < 4) vbF = *(const f16x8*)(BF + ch * 32);
    f0 = __builtin_amdgcn_mfma_f32_16x16x32_f16(pa0[ch], vbF, f0, 0, 0, 0);
    f1 = __builtin_amdgcn_mfma_f32_16x16x32_f16(pa1[ch], vbF, f1, 0, 0, 0);
  }
  if (l15 < 4) {
    const int brow = mh * 32 + quad * 4;
    #pragma unroll
    for (int r = 0; r < 4; ++r) {
      unsafeAtomicAdd(&fcp[(brow + r) * 4 + l15],      f0[r]);
      unsafeAtomicAdd(&fcp[(brow + 16 + r) * 4 + l15], f1[r]);
    }
  }
}

// gates += h @ Whh.T for this block's 32 gate rows; optional fused fc partial.
template<bool FC>
__device__ __forceinline__ void gemm_compute(const f16* wlds, const f16* fcT,
                                             float* gbuf, float* fcp,
                                             int w, int l15, int quad,
                                             const f16x8* pa0, const f16x8* pa1) {
  const int mh = w & 1, kq = w >> 1;
  f32x4v a00 = {0.f, 0.f, 0.f, 0.f}, a01 = a00, a10 = a00, a11 = a00;
  const f16* B0 = wlds + (size_t)l15 * WROW + kq * 512 + quad * 8;
  const f16* B1 = B0 + (size_t)16 * WROW;
  #pragma unroll
  for (int ch = 0; ch < 16; ++ch) {
    f16x8 vb0 = *(const f16x8*)(B0 + ch * 32);
    f16x8 vb1 = *(const f16x8*)(B1 + ch * 32);
    a00 = __builtin_amdgcn_mfma_f32_16x16x32_f16(pa0[ch], vb0, a00, 0, 0, 0);
    a01 = __builtin_amdgcn_mfma_f32_16x16x32_f16(pa0[ch], vb1, a01, 0, 0, 0);
    a10 = __builtin_amdgcn_mfma_f32_16x16x32_f16(pa1[ch], vb0, a10, 0, 0, 0);
    a11 = __builtin_amdgcn_mfma_f32_16x16x32_f16(pa1[ch], vb1, a11, 0, 0, 0);
  }
  const int brow = mh * 32 + quad * 4;
  #pragma unroll
  for (int r = 0; r < 4; ++r) {
    unsafeAtomicAdd(&gbuf[(brow + r)      * 36 +      l15], a00[r]);
    unsafeAtomicAdd(&gbuf[(brow + r)      * 36 + 16 + l15], a01[r]);
    unsafeAtomicAdd(&gbuf[(brow + 16 + r) * 36 +      l15], a10[r]);
    unsafeAtomicAdd(&gbuf[(brow + 16 + r) * 36 + 16 + l15], a11[r]);
  }
  if (FC) fc_compute(fcT, fcp, w, l15, quad, pa0, pa1);
}

extern "C" __global__ void __launch_bounds__(NTHR, 2)
lstm_persistent(Params P) {
  extern __shared__ char smem[];
  f16*   wlds = (f16*)smem;
  float* gbuf = (float*)(smem + 131584);
  float* xv   = (float*)(smem + 140800);
  float* wsm  = (float*)(smem + 141824);
  float* bsm  = (float*)(smem + 142336);
  float* fcp  = (float*)(smem + 142464);
  f16*   fcT  = (f16*)(smem + 143488);

  const int t    = threadIdx.x;
  const int bid  = blockIdx.x;
  const int w    = t >> 6;
  const int l    = t & 63;
  const int l15  = l & 15;
  const int quad = l >> 4;
  const int kq   = w >> 1;
  const int bb   = t >> 3;
  const int jj   = t & 7;
  const int jglob = bid * 8 + jj;
  const int ring = P.ring;
  const size_t GEN = (size_t)NBAT * HID;   // f16 per generation buffer

  // ---------------- one-time cache scrub (cross-dispatch stale lines) ------
  // Safe (r6-proven): no dirty lines exist at entry.
  if (t == 0)
    asm volatile("s_waitcnt vmcnt(0)\n\tbuffer_inv sc0 sc1\n\ts_waitcnt vmcnt(0)" ::: "memory");
  __syncthreads();

  // ---------------- setup (block-local) ----------------
  if (t < 32) {
    int r = t, gr = ((r >> 3) << 11) + bid * 8 + (r & 7);
    ((float4*)wsm)[r] = ((const float4*)P.enc_Wih)[gr];
    bsm[r] = P.enc_bih[gr] + P.enc_bhh[gr];
  }
  fill_weights(P.enc_Whh, bid, wlds, w, l);

  const int len_b = P.lengths[bb];
  const float4 fcb = ((const float4*)P.fc_b)[0];
  float hreg = 0.f, creg = 0.f;

  // ---------------- encoder: 128 masked steps ----------------
  for (int ts = 0; ts < TENC; ++ts) {
    const size_t roff = (size_t)(ring ? ts : (ts & 1)) * GEN;
    const size_t woff = (size_t)(ring ? (ts + 1) : ((ts + 1) & 1)) * GEN;
    // --- pre-wait work (h-independent): x load, gbuf=bias, xv stage ---
    float4 xvv;
    if (t < NBAT) xvv = ((const float4*)P.x)[t * TENC + ts];
    for (int e = t; e < 2048; e += NTHR) {
      int b = e >> 5, n = e & 31;
      gbuf[b * 36 + n] = bsm[n];
    }
    if (t < NBAT) ((float4*)xv)[t] = xvv;
    ldsbar();                                   // gbuf + xv ready
    // --- wait for this wave's K-slice of h_ts, prefetch, GEMM ---
    if (ts > 0) {
      wait_slice(P.bar, kq, l, (unsigned)ts);
      f16x8 pa0[16], pa1[16];
      gemm_prefetch(P.h16 + roff, ring, w, l15, quad, pa0, pa1);
      if (!ring) waitpa();    // asm loads need the explicit drain (rule #18)
      gemm_compute<false>(wlds, fcT, gbuf, fcp, w, l15, quad, pa0, pa1);
    }
    ldsbar();
    {
      const float4 xb  = ((const float4*)xv)[bb];
      const float4 wi4 = ((const float4*)wsm)[jj];
      const float4 wf4 = ((const float4*)wsm)[8 + jj];
      const float4 wg4 = ((const float4*)wsm)[16 + jj];
      const float4 wo4 = ((const float4*)wsm)[24 + jj];
      float gi = gbuf[bb * 36 + jj]      + DOT4(xb, wi4);
      float gf = gbuf[bb * 36 + 8 + jj]  + DOT4(xb, wf4);
      float gg = gbuf[bb * 36 + 16 + jj] + DOT4(xb, wg4);
      float go = gbuf[bb * 36 + 24 + jj] + DOT4(xb, wo4);
      float ii = 1.f / (1.f + expf(-gi));
      float ff = 1.f / (1.f + expf(-gf));
      float g  = tanhf(gg);
      float oo = 1.f / (1.f + expf(-go));
      float cn = ff * creg + ii * g;
      float hn = oo * tanhf(cn);
      if (ts < len_b) { creg = cn; hreg = hn; }   // packed-sequence freeze
      unsigned hv = (unsigned)__builtin_bit_cast(unsigned short, (f16)hreg);
      unsigned v1 = __shfl_down(hv, 1), v2 = __shfl_down(hv, 2), v3 = __shfl_down(hv, 3);
      if ((t & 3) == 0) {   // tiled write: [grp=bid][batch=bb][8] -> full lines
        unsigned long long pk = (unsigned long long)hv | ((unsigned long long)v1 << 16)
                              | ((unsigned long long)v2 << 32) | ((unsigned long long)v3 << 48);
        astore_u64(P.h16 + woff + (size_t)bid * 512 + (size_t)bb * 8 + (jj & 4), pk);
      }
    }
    __syncthreads();                              // drains h16 stores (all waves)
    if (t == 0) arrive(P.bar, bid, (unsigned)(ts + 1));
  }

  // ------- transition (block-local; overlaps other XCDs' tails) -------
  fill_weights(P.dec_Whh, bid, wlds, w, l);
  #pragma unroll
  for (int rr = 0; rr < 4; ++rr) {       // M1 = dec_Wih@emb_W straight into LDS
    int r = w * 4 + rr, gr = ((r >> 3) << 11) + bid * 8 + (r & 7);
    const float* wr = P.dec_Wih + (size_t)gr * HID;
    float a0 = 0.f, a1 = 0.f, a2 = 0.f, a3 = 0.f, ab = 0.f;
    for (int k = l; k < HID; k += 64) {
      float wv = wr[k];
      float4 e = ((const float4*)P.emb_W)[k];
      a0 += wv * e.x; a1 += wv * e.y; a2 += wv * e.z; a3 += wv * e.w;
      ab += wv * P.emb_b[k];
    }
    #pragma unroll
    for (int off = 32; off > 0; off >>= 1) {
      a0 += __shfl_xor(a0, off); a1 += __shfl_xor(a1, off);
      a2 += __shfl_xor(a2, off); a3 += __shfl_xor(a3, off);
      ab += __shfl_xor(ab, off);
    }
    if (l == 0) {
      wsm[r * 4 + 0] = a0; wsm[r * 4 + 1] = a1; wsm[r * 4 + 2] = a2; wsm[r * 4 + 3] = a3;
      bsm[r] = ab + P.dec_bih[gr] + P.dec_bhh[gr];
    }
  }
  for (int i = t; i < 2048; i += NTHR) {   // fcT[d][k] = (f16)fc_W[d][k]
    int d = i >> 9, k4 = i & 511;
    float4 v = ((const float4*)P.fc_W)[i];
    f16x4 h4; h4[0] = (f16)v.x; h4[1] = (f16)v.y; h4[2] = (f16)v.z; h4[3] = (f16)v.w;
    *(f16x4*)(fcT + (size_t)d * FROW + k4 * 4) = h4;
  }
  ldsbar();   // block-local: wlds/wsm/bsm/fcT visible

  // ---------------- decoder: 64 autoregressive steps ----------------
  for (int s = 0; s < TDEC; ++s) {
    const int rgen = TENC + s, wgen = rgen + 1;
    const size_t roff = (size_t)(ring ? rgen : (rgen & 1)) * GEN;
    const size_t woff = (size_t)(ring ? wgen : (wgen & 1)) * GEN;
    // --- pre-wait work: fcp zero + gbuf=bias ---
    if (t < 256) fcp[t] = 0.f;
    for (int e = t; e < 2048; e += NTHR) {
      int b = e >> 5, n = e & 31;
      gbuf[b * 36 + n] = bsm[n];
    }
    ldsbar();
    // --- wait for h_rgen, then prefetch + GEMM (+fused fc) ---
    wait_slice(P.bar, kq, l, (unsigned)rgen);
    f16x8 pa0[16], pa1[16];
    gemm_prefetch(P.h16 + roff, ring, w, l15, quad, pa0, pa1);
    if (!ring) waitpa();
    gemm_compute<true>(wlds, fcT, gbuf, fcp, w, l15, quad, pa0, pa1);
    ldsbar();
    if (t < NBAT) {          // xv = input for this step = fc(h_prev) (or x0 at s==0)
      float4 o;
      if (s == 0) {
        o = ((const float4*)P.x)[t * TENC + (P.lengths[t] - 1)];
      } else {
        float4 p = ((const float4*)fcp)[t];
        o.x = fcb.x + p.x; o.y = fcb.y + p.y; o.z = fcb.z + p.z; o.w = fcb.w + p.w;
      }
      ((float4*)xv)[t] = o;
      if (s >= 1 && bid == s)                   // rotating prediction writer
        ((float4*)P.dst)[t * TDEC + (s - 1)] = o;
    }
    ldsbar();
    {
      const float4 xb  = ((const float4*)xv)[bb];
      const float4 wi4 = ((const float4*)wsm)[jj];
      const float4 wf4 = ((const float4*)wsm)[8 + jj];
      const float4 wg4 = ((const float4*)wsm)[16 + jj];
      const float4 wo4 = ((const float4*)wsm)[24 + jj];
      float gi = gbuf[bb * 36 + jj]      + DOT4(xb, wi4);
      float gf = gbuf[bb * 36 + 8 + jj]  + DOT4(xb, wf4);
      float gg = gbuf[bb * 36 + 16 + jj] + DOT4(xb, wg4);
      float go = gbuf[bb * 36 + 24 + jj] + DOT4(xb, wo4);
      float ii = 1.f / (1.f + expf(-gi));
      float ff = 1.f / (1.f + expf(-gf));
      float g  = tanhf(gg);
      float oo = 1.f / (1.f + expf(-go));
      creg = ff * creg + ii * g;
      hreg = oo * tanhf(creg);
      unsigned hv = (unsigned)__builtin_bit_cast(unsigned short, (f16)hreg);
      unsigned v1 = __shfl_down(hv, 1), v2 = __shfl_down(hv, 2), v3 = __shfl_down(hv, 3);
      if ((t & 3) == 0) {
        unsigned long long pk = (unsigned long long)hv | ((unsigned long long)v1 << 16)
                              | ((unsigned long long)v2 << 32) | ((unsigned long long)v3 << 48);
        astore_u64(P.h16 + woff + (size_t)bid * 512 + (size_t)bb * 8 + (jj & 4), pk);
      }
    }
    __syncthreads();
    if (t == 0) arrive(P.bar, bid, (unsigned)wgen);
  }

  // ---------------- epilogue: out(63) = fc(H_63) by block 0 ----------------
  if (bid == 0) {
    wait_slice(P.bar, kq, l, (unsigned)(TENC + TDEC));
    if (t < 256) fcp[t] = 0.f;
    f16x8 pa0[16], pa1[16];
    gemm_prefetch(P.h16 + (size_t)(ring ? (TENC + TDEC) : ((TENC + TDEC) & 1)) * GEN,
                  ring, w, l15, quad, pa0, pa1);
    ldsbar();
    waitpa();
    fc_compute(fcT, fcp, w, l15, quad, pa0, pa1);
    ldsbar();
    if (t < NBAT) {
      float4 p = ((const float4*)fcp)[t];
      float4 o;
      o.x = fcb.x + p.x; o.y = fcb.y + p.y; o.z = fcb.z + p.z; o.w = fcb.w + p.w;
      ((float4*)P.dst)[t * TDEC + 63] = o;       // predictions[b][63]
      ((float4*)(P.dst + 16384))[t]   = o;       // out
    }
  }
  P.dst[16640  + (size_t)bb * HID + jglob] = hreg;   // h
  P.dst[147712 + (size_t)bb * HID + jglob] = creg;   // c
}

extern "C" void kernel_launch(void* const* d_in, const int* in_sizes, int n_in,
                              void* d_out, int out_size, void* d_ws, size_t ws_size,
                              hipStream_t stream) {
  (void)in_sizes; (void)n_in; (void)out_size;
  Params P;
  P.x        = (const float*)d_in[0];
  P.lengths  = (const int*)  d_in[1];
  // d_in[2] = target_len (constant 64)
  P.enc_Wih  = (const float*)d_in[3];
  P.enc_Whh  = (const float*)d_in[4];
  P.enc_bih  = (const float*)d_in[5];
  P.enc_bhh  = (const float*)d_in[6];
  P.emb_W    = (const float*)d_in[7];
  P.emb_b    = (const float*)d_in[8];
  P.dec_Wih  = (const float*)d_in[9];
  P.dec_Whh  = (const float*)d_in[10];
  P.dec_bih  = (const float*)d_in[11];
  P.dec_bhh  = (const float*)d_in[12];
  P.fc_W     = (const float*)d_in[13];
  P.fc_b     = (const float*)d_in[14];
  P.dst      = (float*)d_out;

  char* ws = (char*)d_ws;
  const size_t slot = (size_t)NBAT * HID * sizeof(_Float16);   // 262144 B per generation
  const size_t ring_bytes = (size_t)(TENC + TDEC + 1) * slot;  // 193 slots = 50,593,792 B
  int ring = (ws_size >= ring_bytes + 16384) ? 1 : 0;
  P.h16  = (f16*)ws;
  P.bar  = (unsigned*)(ws + (ring ? ring_bytes : 2 * slot));
  P.ring = ring;

  hipMemsetAsync(P.bar, 0, 12288, stream);           // ws is poisoned 0xAA

  hipFuncSetAttribute((const void*)lstm_persistent,
                      hipFuncAttributeMaxDynamicSharedMemorySize, SMEM_BYTES);
  void* args[] = { &P };
  hipLaunchCooperativeKernel((const void*)lstm_persistent, dim3(NBLK), dim3(NTHR),
                             args, SMEM_BYTES, stream);
}